// Round 2
// baseline (2790.759 us; speedup 1.0000x reference)
//
#include <hip/hip_runtime.h>
#include <cstdint>
#include <cstddef>

// Extractor_N2V: out = BN(seg_mean(x) + eps1*x) @ W2^T + b2, x = h@W1^T + b1
// Folded: g = seg_sum(h[src],dst)/deg + eps1*h; out = g@M^T + c with
// M = W2 diag(s) W1, BN stats computed analytically from colsum(g) and G^T G.
//
// Aggregation strategy (R2): bucket edges by dst>>6 (64 nodes/bucket),
// then one block per bucket accumulates into a 64x128 LDS tile with
// ds_add_f32. No per-node CSR, no random 4B scatter (that was 196MB of
// write-allocate traffic in R1).

#define IN_DIM 128
#define H_DIM 256
#define NPB 64          // nodes per bucket (dst>>6)
#define MAXB 1792       // LDS array capacity for bucket counters (>= B)

static inline size_t align256(size_t x){ return (x + 255) & ~(size_t)255; }

// ---- bucket histogram: LDS-local counts, one global atomic per (block,bucket)
__global__ __launch_bounds__(256) void k_bcount(const int* __restrict__ dst,
                        int* __restrict__ gcount, int E_, int B_) {
  __shared__ int lc[MAXB];
  int t = threadIdx.x;
  for (int i = t; i < B_; i += 256) lc[i] = 0;
  __syncthreads();
  int per = (E_ + gridDim.x - 1) / gridDim.x;
  int beg = blockIdx.x * per, end = min(beg + per, E_);
  for (int i = beg + t; i < end; i += 256) atomicAdd(&lc[dst[i] >> 6], 1);
  __syncthreads();
  for (int i = t; i < B_; i += 256) { int v = lc[i]; if (v) atomicAdd(&gcount[i], v); }
}

// ---- exclusive scan of B_ bucket counts (single block, 256 threads x 7 slots)
__global__ __launch_bounds__(256) void k_bscan(const int* __restrict__ gcount,
                        int* __restrict__ boff, int* __restrict__ gcursor, int B_) {
  __shared__ int part[256];
  __shared__ int vals[MAXB];
  int t = threadIdx.x;
  int base = t * 7;
  int s = 0;
  #pragma unroll
  for (int k = 0; k < 7; k++) {
    int idx = base + k;
    int v = (idx < B_) ? gcount[idx] : 0;
    vals[idx < MAXB ? idx : MAXB-1] = s;  // exclusive within-thread
    s += v;
  }
  part[t] = s;
  __syncthreads();
  for (int off = 1; off < 256; off <<= 1) {
    int a = (t >= off) ? part[t - off] : 0;
    __syncthreads();
    part[t] += a;
    __syncthreads();
  }
  int pbase = (t > 0) ? part[t - 1] : 0;
  #pragma unroll
  for (int k = 0; k < 7; k++) {
    int idx = base + k;
    if (idx < B_) { int o = pbase + vals[idx]; boff[idx] = o; gcursor[idx] = o; }
  }
  if (t == 255) boff[B_] = part[255];   // == E
}

// ---- two-pass rank & scatter: pairs[pos] = src | (dstLocal<<20), bucket-contiguous
__global__ __launch_bounds__(256) void k_bfill(const int* __restrict__ src,
                        const int* __restrict__ dst, int* __restrict__ gcursor,
                        unsigned int* __restrict__ pairs, int E_, int B_) {
  __shared__ int lc[MAXB];
  int t = threadIdx.x;
  for (int i = t; i < B_; i += 256) lc[i] = 0;
  __syncthreads();
  int per = (E_ + gridDim.x - 1) / gridDim.x;
  int beg = blockIdx.x * per, end = min(beg + per, E_);
  for (int i = beg + t; i < end; i += 256) atomicAdd(&lc[dst[i] >> 6], 1);
  __syncthreads();
  // reserve contiguous range per (block,bucket); lc becomes the running cursor
  for (int i = t; i < B_; i += 256) {
    int v = lc[i];
    lc[i] = v ? atomicAdd(&gcursor[i], v) : 0;
  }
  __syncthreads();
  for (int i = beg + t; i < end; i += 256) {
    int d = dst[i];
    int b = d >> 6;
    int p = atomicAdd(&lc[b], 1);
    pairs[p] = (unsigned int)src[i] | ((unsigned int)(d & 63) << 20);
  }
}

// ---- per-bucket aggregation: pooled[64][128] in LDS, then g = pooled/deg + eps1*h
__global__ __launch_bounds__(256) void k_agg(const float* __restrict__ h,
                        const unsigned int* __restrict__ pairs,
                        const int* __restrict__ boff, const float* __restrict__ eps1,
                        float* __restrict__ g, int N_) {
  __shared__ float pooled[NPB][IN_DIM];
  __shared__ int ldeg[NPB];
  int t = threadIdx.x, b = blockIdx.x;
  for (int i = t; i < NPB * (IN_DIM/4); i += 256) ((float4*)pooled)[i] = make_float4(0.f,0.f,0.f,0.f);
  for (int i = t; i < NPB; i += 256) ldeg[i] = 0;
  __syncthreads();
  int beg = boff[b], end = boff[b + 1];
  int w = t >> 6, lane = t & 63;
  const float2* h2 = (const float2*)h;
  int e = beg + w;
  for (; e + 4 < end; e += 8) {
    unsigned int pk0 = pairs[e], pk1 = pairs[e + 4];
    int s0 = pk0 & 0xFFFFF, d0 = pk0 >> 20;
    int s1 = pk1 & 0xFFFFF, d1 = pk1 >> 20;
    float2 v0 = h2[(size_t)s0 * 64 + lane];
    float2 v1 = h2[(size_t)s1 * 64 + lane];
    atomicAdd(&pooled[d0][lane * 2 + 0], v0.x);
    atomicAdd(&pooled[d0][lane * 2 + 1], v0.y);
    atomicAdd(&pooled[d1][lane * 2 + 0], v1.x);
    atomicAdd(&pooled[d1][lane * 2 + 1], v1.y);
    if (lane == 0) { atomicAdd(&ldeg[d0], 1); atomicAdd(&ldeg[d1], 1); }
  }
  if (e < end) {
    unsigned int pk0 = pairs[e];
    int s0 = pk0 & 0xFFFFF, d0 = pk0 >> 20;
    float2 v0 = h2[(size_t)s0 * 64 + lane];
    atomicAdd(&pooled[d0][lane * 2 + 0], v0.x);
    atomicAdd(&pooled[d0][lane * 2 + 1], v0.y);
    if (lane == 0) atomicAdd(&ldeg[d0], 1);
  }
  __syncthreads();
  int nb = b * NPB;
  float e1 = eps1[0];
  for (int i = t; i < NPB * 64; i += 256) {
    int ln = i >> 6, c = i & 63;
    int node = nb + ln;
    if (node < N_) {
      float dg = (float)ldeg[ln];
      float2 hv = h2[(size_t)node * 64 + c];
      float2 o;
      o.x = pooled[ln][c * 2 + 0] / dg + e1 * hv.x;   // deg==0 -> inf/nan, matches ref
      o.y = pooled[ln][c * 2 + 1] / dg + e1 * hv.y;
      ((float2*)g)[(size_t)node * 64 + c] = o;
    }
  }
}

// S2 = G^T G (128x128) and colsum(g) via block-local register tiles + one atomic pass
__global__ __launch_bounds__(256) void k_gram(const float* __restrict__ g,
                       float* __restrict__ S2, float* __restrict__ colsum, int N_) {
  __shared__ float gs[64][129];
  int t = threadIdx.x;
  int tx = t & 15, ty = t >> 4;           // C rows: tx+16u, C cols: ty+16v
  float acc[8][8];
  #pragma unroll
  for (int u=0;u<8;u++)
    #pragma unroll
    for (int v=0;v<8;v++) acc[u][v]=0.f;
  float cs = 0.f;
  for (int r0 = blockIdx.x*64; r0 < N_; r0 += gridDim.x*64){
    __syncthreads();
    for (int idx = t; idx < 64*32; idx += 256){
      int r = idx >> 5, p = idx & 31;
      float4 v = {0.f,0.f,0.f,0.f};
      if (r0 + r < N_) v = ((const float4*)g)[(size_t)(r0+r)*32 + p];
      gs[r][p*4+0]=v.x; gs[r][p*4+1]=v.y; gs[r][p*4+2]=v.z; gs[r][p*4+3]=v.w;
    }
    __syncthreads();
    #pragma unroll 4
    for (int r=0;r<64;r++){
      float a[8], b[8];
      #pragma unroll
      for (int u=0;u<8;u++){ a[u]=gs[r][tx+16*u]; b[u]=gs[r][ty+16*u]; }
      #pragma unroll
      for (int u=0;u<8;u++)
        #pragma unroll
        for (int v=0;v<8;v++) acc[u][v] += a[u]*b[v];
    }
    if (t < 128){
      float c2=0.f;
      #pragma unroll 4
      for (int r=0;r<64;r++) c2 += gs[r][t];
      cs += c2;
    }
  }
  #pragma unroll
  for (int u=0;u<8;u++)
    #pragma unroll
    for (int v=0;v<8;v++)
      atomicAdd(&S2[(tx+16*u)*128 + (ty+16*v)], acc[u][v]);
  if (t < 128) atomicAdd(&colsum[t], cs);
}

// q[j] = w_j S2 w_j^T  (S2 symmetric -> column access is coalesced)
__global__ void k_quad(const float* __restrict__ W1, const float* __restrict__ S2,
                       float* __restrict__ qbuf) {
  __shared__ float ws[128];
  __shared__ float red[128];
  int j = blockIdx.x, d = threadIdx.x;
  ws[d] = W1[(size_t)j*128 + d];
  __syncthreads();
  float r = 0.f;
  for (int dp=0; dp<128; dp++) r += S2[dp*128 + d]*ws[dp];
  red[d] = r*ws[d];
  __syncthreads();
  for (int off=64; off>0; off>>=1){ if (d<off) red[d]+=red[d+off]; __syncthreads(); }
  if (d==0) qbuf[j] = red[0];
}

// per-channel stats -> s (scale), and c (fused output bias)
__global__ void k_stats2(const float* __restrict__ W1, const float* __restrict__ b1,
                         const float* __restrict__ W2, const float* __restrict__ b2,
                         const float* __restrict__ gamma, const float* __restrict__ beta,
                         const float* __restrict__ eps1, const float* __restrict__ colsum,
                         const float* __restrict__ qbuf, float* __restrict__ sbuf,
                         float* __restrict__ cbuf, int N_) {
  __shared__ float mg[128];
  __shared__ float tt[256];
  int t = threadIdx.x;
  float invN = 1.f/(float)N_;
  if (t < 128) mg[t] = colsum[t]*invN;
  __syncthreads();
  float e1 = eps1[0];
  float bpp = (1.f + e1)*b1[t];
  const float* w = W1 + (size_t)t*128;
  float mx = bpp;
  for (int d=0; d<128; d++) mx += w[d]*mg[d];
  float ex2 = qbuf[t]*invN + 2.f*bpp*(mx - bpp) + bpp*bpp;
  float var = ex2 - mx*mx;
  float s = gamma[t]*rsqrtf(var + 1e-5f);
  sbuf[t] = s;
  tt[t] = (bpp - mx)*s + beta[t];
  __syncthreads();
  float c = b2[t];
  for (int j=0;j<256;j++) c += tt[j]*W2[(size_t)t*256 + j];
  cbuf[t] = c;
}

// M[k,d] = sum_j W2[k,j] * s[j] * W1[j,d]
__global__ void k_matM(const float* __restrict__ W1, const float* __restrict__ W2,
                       const float* __restrict__ sbuf, float* __restrict__ Mm) {
  __shared__ float ws[256];
  int k = blockIdx.x, d = threadIdx.x;   // 128 threads
  ws[d]       = W2[(size_t)k*256 + d]       * sbuf[d];
  ws[d + 128] = W2[(size_t)k*256 + d + 128] * sbuf[d + 128];
  __syncthreads();
  float acc = 0.f;
  for (int j=0;j<256;j++) acc += ws[j]*W1[(size_t)j*128 + d];  // coalesced over d
  Mm[(size_t)k*128 + d] = acc;
}

// out[i,k] = g[i,:] . M[k,:] + c[k]   tile 64 rows x 256 cols, K chunked by 32
__global__ __launch_bounds__(256) void k_out(const float* __restrict__ g, const float* __restrict__ Mm,
                     const float* __restrict__ cb, float* __restrict__ out, int N_) {
  __shared__ float gs[64][33];
  __shared__ float Ms[256][33];
  int t = threadIdx.x;
  int tx = t & 15, ty = t >> 4;   // thread: rows tx*4..+3, cols ty*16..+15
  int i0 = blockIdx.x*64;
  float acc[4][16];
  #pragma unroll
  for (int r=0;r<4;r++)
    #pragma unroll
    for (int q=0;q<16;q++) acc[r][q]=0.f;
  for (int ch=0; ch<4; ch++){
    __syncthreads();
    #pragma unroll
    for (int l=0;l<2;l++){
      int idx = t + l*256;
      int r = idx >> 3, p = idx & 7;
      float4 v = {0.f,0.f,0.f,0.f};
      if (i0 + r < N_) v = *(const float4*)&g[(size_t)(i0+r)*128 + ch*32 + p*4];
      gs[r][p*4+0]=v.x; gs[r][p*4+1]=v.y; gs[r][p*4+2]=v.z; gs[r][p*4+3]=v.w;
    }
    #pragma unroll
    for (int l=0;l<8;l++){
      int idx = t + l*256;
      int q = idx >> 3, p = idx & 7;
      float4 v = *(const float4*)&Mm[(size_t)q*128 + ch*32 + p*4];
      Ms[q][p*4+0]=v.x; Ms[q][p*4+1]=v.y; Ms[q][p*4+2]=v.z; Ms[q][p*4+3]=v.w;
    }
    __syncthreads();
    #pragma unroll 4
    for (int dd=0; dd<32; dd++){
      float a[4], b[16];
      #pragma unroll
      for (int r=0;r<4;r++) a[r] = gs[tx*4+r][dd];
      #pragma unroll
      for (int q=0;q<16;q++) b[q] = Ms[ty*16+q][dd];
      #pragma unroll
      for (int r=0;r<4;r++)
        #pragma unroll
        for (int q=0;q<16;q++) acc[r][q] += a[r]*b[q];
    }
  }
  float cv[16];
  #pragma unroll
  for (int q=0;q<16;q++) cv[q] = cb[ty*16+q];
  #pragma unroll
  for (int r=0;r<4;r++){
    int i = i0 + tx*4 + r;
    if (i < N_){
      #pragma unroll
      for (int q4=0;q4<4;q4++){
        float4 o;
        o.x = acc[r][q4*4+0]+cv[q4*4+0];
        o.y = acc[r][q4*4+1]+cv[q4*4+1];
        o.z = acc[r][q4*4+2]+cv[q4*4+2];
        o.w = acc[r][q4*4+3]+cv[q4*4+3];
        *(float4*)&out[(size_t)i*256 + ty*16 + q4*4] = o;
      }
    }
  }
}

extern "C" void kernel_launch(void* const* d_in, const int* in_sizes, int n_in,
                              void* d_out, int out_size, void* d_ws, size_t ws_size,
                              hipStream_t stream) {
  const float* h     = (const float*)d_in[0];
  const int*   esrc  = (const int*)d_in[1];
  const int*   edst  = (const int*)d_in[2];
  const float* W1    = (const float*)d_in[3];
  const float* b1    = (const float*)d_in[4];
  const float* W2    = (const float*)d_in[5];
  const float* b2    = (const float*)d_in[6];
  const float* gamma = (const float*)d_in[7];
  const float* beta  = (const float*)d_in[8];
  const float* eps1  = (const float*)d_in[9];
  int N = in_sizes[0] / IN_DIM;
  int E = in_sizes[1];
  int B = (N + NPB - 1) / NPB;          // 1563 buckets for N=100000
  float* out = (float*)d_out;

  char* ws = (char*)d_ws;
  size_t off = 0;
  auto alloc = [&](size_t bytes)->char* {
    char* p = ws + off; off = align256(off + bytes); return p;
  };
  int*   gcount   = (int*)  alloc((size_t)B*4);
  int*   boff     = (int*)  alloc(((size_t)B+1)*4);
  int*   gcursor  = (int*)  alloc((size_t)B*4);
  unsigned int* pairs = (unsigned int*)alloc((size_t)E*4);
  float* S2       = (float*)alloc(128*128*4 + 128*4);   // + colsum tail
  float* colsum   = S2 + 128*128;
  float* qbuf     = (float*)alloc(256*4);
  float* sbuf     = (float*)alloc(256*4);
  float* cbuf     = (float*)alloc(256*4);
  float* Mm       = (float*)alloc(256*128*4);
  float* g        = (float*)alloc((size_t)N*128*4);
  (void)ws_size; (void)n_in; (void)out_size;

  hipMemsetAsync(gcount, 0, (size_t)B*4, stream);
  hipMemsetAsync(S2, 0, 128*128*4 + 128*4, stream);

  k_bcount<<<512, 256, 0, stream>>>(edst, gcount, E, B);
  k_bscan<<<1, 256, 0, stream>>>(gcount, boff, gcursor, B);
  k_bfill<<<512, 256, 0, stream>>>(esrc, edst, gcursor, pairs, E, B);
  k_agg<<<B, 256, 0, stream>>>(h, pairs, boff, eps1, g, N);
  k_gram<<<512, 256, 0, stream>>>(g, S2, colsum, N);
  k_quad<<<256, 128, 0, stream>>>(W1, S2, qbuf);
  k_stats2<<<1, 256, 0, stream>>>(W1, b1, W2, b2, gamma, beta, eps1, colsum, qbuf, sbuf, cbuf, N);
  k_matM<<<256, 128, 0, stream>>>(W1, W2, sbuf, Mm);
  k_out<<<(N+63)/64, 256, 0, stream>>>(g, Mm, cbuf, out, N);
}

// Round 3
// 580.309 us; speedup vs baseline: 4.8091x; 4.8091x over previous
//
#include <hip/hip_runtime.h>
#include <cstdint>
#include <cstddef>

// Extractor_N2V: out = BN(seg_mean(x) + eps1*x) @ W2^T + b2, x = h@W1^T + b1
// Folded: g = seg_sum(h[src],dst)/deg + eps1*h; out = g@M^T + c with
// M = W2 diag(s) W1, BN stats computed analytically from colsum(g) and G^T G.
//
// R3 aggregation: bucket-sort edges by dst>>8 into CSR (contiguous-chunk
// scatter, no 4B random write-allocate), then one-wave-per-node register
// gather reading bf16 h rows (256B/edge).

#define IN_DIM 128
#define H_DIM 256
#define NPB 256         // nodes per bucket (dst>>8)
#define MAXB 1792       // bscan capacity (B = ceil(N/256) = 391)

typedef unsigned int uint32;
typedef unsigned short ushort16;

static inline size_t align256(size_t x){ return (x + 255) & ~(size_t)255; }

__device__ inline uint32 f2bf(float f){
  uint32 u = __float_as_uint(f);
  return (u + 0x7FFFu + ((u >> 16) & 1u)) >> 16;   // RNE
}

// ---- h (fp32) -> hb (bf16 packed)
__global__ __launch_bounds__(256) void k_h2b(const float* __restrict__ h,
                        uint32* __restrict__ hb2, int n4) {
  int i = blockIdx.x*256 + threadIdx.x;
  int stride = gridDim.x*256;
  for (; i < n4; i += stride) {
    float4 v = ((const float4*)h)[i];
    uint32 lo = f2bf(v.x) | (f2bf(v.y) << 16);
    uint32 hi = f2bf(v.z) | (f2bf(v.w) << 16);
    ((uint2*)hb2)[i] = make_uint2(lo, hi);
  }
}

// ---- bucket histogram: LDS-local counts, one global atomic per (block,bucket)
__global__ __launch_bounds__(256) void k_bcount(const int* __restrict__ dst,
                        int* __restrict__ gcount, int E_, int B_) {
  __shared__ int lc[512];
  int t = threadIdx.x;
  for (int i = t; i < B_; i += 256) lc[i] = 0;
  __syncthreads();
  int per = (E_ + gridDim.x - 1) / gridDim.x;
  int beg = blockIdx.x * per, end = min(beg + per, E_);
  for (int i = beg + t; i < end; i += 256) atomicAdd(&lc[dst[i] >> 8], 1);
  __syncthreads();
  for (int i = t; i < B_; i += 256) { int v = lc[i]; if (v) atomicAdd(&gcount[i], v); }
}

// ---- exclusive scan of B_ bucket counts; also row_ptr[N]=E
__global__ __launch_bounds__(256) void k_bscan(const int* __restrict__ gcount,
                        int* __restrict__ boff, int* __restrict__ gcursor,
                        int* __restrict__ row_ptr, int B_, int N_) {
  __shared__ int part[256];
  __shared__ int vals[MAXB];
  int t = threadIdx.x;
  int base = t * 7;
  int s = 0;
  #pragma unroll
  for (int k = 0; k < 7; k++) {
    int idx = base + k;
    int v = (idx < B_) ? gcount[idx] : 0;
    vals[idx < MAXB ? idx : MAXB-1] = s;
    s += v;
  }
  part[t] = s;
  __syncthreads();
  for (int off = 1; off < 256; off <<= 1) {
    int a = (t >= off) ? part[t - off] : 0;
    __syncthreads();
    part[t] += a;
    __syncthreads();
  }
  int pbase = (t > 0) ? part[t - 1] : 0;
  #pragma unroll
  for (int k = 0; k < 7; k++) {
    int idx = base + k;
    if (idx < B_) { int o = pbase + vals[idx]; boff[idx] = o; gcursor[idx] = o; }
  }
  if (t == 255) { boff[B_] = part[255]; row_ptr[N_] = part[255]; }
}

// ---- chunked scatter: pairs[pos] = src | (dstLocal<<20), bucket-contiguous
__global__ __launch_bounds__(256) void k_bfill(const int* __restrict__ src,
                        const int* __restrict__ dst, int* __restrict__ gcursor,
                        uint32* __restrict__ pairs, int E_, int B_) {
  __shared__ int lc[512];
  int t = threadIdx.x;
  for (int i = t; i < B_; i += 256) lc[i] = 0;
  __syncthreads();
  int per = (E_ + gridDim.x - 1) / gridDim.x;
  int beg = blockIdx.x * per, end = min(beg + per, E_);
  for (int i = beg + t; i < end; i += 256) atomicAdd(&lc[dst[i] >> 8], 1);
  __syncthreads();
  for (int i = t; i < B_; i += 256) {
    int v = lc[i];
    lc[i] = v ? atomicAdd(&gcursor[i], v) : 0;
  }
  __syncthreads();
  for (int i = beg + t; i < end; i += 256) {
    int d = dst[i];
    int b = d >> 8;
    int p = atomicAdd(&lc[b], 1);
    pairs[p] = (uint32)src[i] | ((uint32)(d & 255) << 20);
  }
}

// ---- per-bucket counting sort -> CSR eidx + row_ptr (two passes, no big LDS stage)
__global__ __launch_bounds__(256) void k_bsort(const uint32* __restrict__ pairs,
                        const int* __restrict__ boff, int* __restrict__ row_ptr,
                        int* __restrict__ eidx, int N_) {
  __shared__ int cnt[256];
  __shared__ int scan[256];
  __shared__ int cursor[256];
  int t = threadIdx.x, b = blockIdx.x;
  cnt[t] = 0;
  __syncthreads();
  int beg = boff[b], end = boff[b + 1];
  for (int i = beg + t; i < end; i += 256) atomicAdd(&cnt[pairs[i] >> 20], 1);
  __syncthreads();
  int v = cnt[t];
  scan[t] = v;
  __syncthreads();
  for (int off = 1; off < 256; off <<= 1) {
    int a = (t >= off) ? scan[t - off] : 0;
    __syncthreads();
    scan[t] += a;
    __syncthreads();
  }
  int ex = scan[t] - v;            // exclusive prefix within bucket
  cursor[t] = ex;
  int node = b * NPB + t;
  if (node < N_) row_ptr[node] = beg + ex;
  __syncthreads();
  for (int i = beg + t; i < end; i += 256) {
    uint32 pk = pairs[i];
    int j = pk >> 20;
    int p = atomicAdd(&cursor[j], 1);
    eidx[beg + p] = (int)(pk & 0xFFFFF);
  }
}

// ---- one wave per node, register accumulation, bf16 rows (256B/edge)
__global__ __launch_bounds__(256) void k_gather(const uint32* __restrict__ hb,
                        const float* __restrict__ h,
                        const int* __restrict__ row_ptr, const int* __restrict__ eidx,
                        const float* __restrict__ eps1, float* __restrict__ g, int N_) {
  int w = (int)((blockIdx.x*blockDim.x + threadIdx.x) >> 6);
  int lane = threadIdx.x & 63;
  if (w >= N_) return;
  int beg = row_ptr[w], end = row_ptr[w+1];
  float2 a0 = {0.f,0.f}, a1 = {0.f,0.f}, a2 = {0.f,0.f}, a3 = {0.f,0.f};
  int e = beg;
  for (; e + 3 < end; e += 4) {
    int s0 = eidx[e], s1 = eidx[e+1], s2 = eidx[e+2], s3 = eidx[e+3];
    uint32 u0 = hb[(size_t)s0*64 + lane];
    uint32 u1 = hb[(size_t)s1*64 + lane];
    uint32 u2 = hb[(size_t)s2*64 + lane];
    uint32 u3 = hb[(size_t)s3*64 + lane];
    a0.x += __uint_as_float(u0 << 16); a0.y += __uint_as_float(u0 & 0xFFFF0000u);
    a1.x += __uint_as_float(u1 << 16); a1.y += __uint_as_float(u1 & 0xFFFF0000u);
    a2.x += __uint_as_float(u2 << 16); a2.y += __uint_as_float(u2 & 0xFFFF0000u);
    a3.x += __uint_as_float(u3 << 16); a3.y += __uint_as_float(u3 & 0xFFFF0000u);
  }
  for (; e < end; e++) {
    int s0 = eidx[e];
    uint32 u0 = hb[(size_t)s0*64 + lane];
    a0.x += __uint_as_float(u0 << 16); a0.y += __uint_as_float(u0 & 0xFFFF0000u);
  }
  float degf = (float)(end - beg);
  float e1 = eps1[0];
  float2 hv = ((const float2*)h)[(size_t)w*64 + lane];
  float2 o;
  o.x = ((a0.x + a1.x) + (a2.x + a3.x)) / degf + e1 * hv.x;
  o.y = ((a0.y + a1.y) + (a2.y + a3.y)) / degf + e1 * hv.y;
  ((float2*)g)[(size_t)w*64 + lane] = o;
}

// S2 = G^T G (128x128) and colsum(g) via block-local register tiles + one atomic pass
__global__ __launch_bounds__(256) void k_gram(const float* __restrict__ g,
                       float* __restrict__ S2, float* __restrict__ colsum, int N_) {
  __shared__ float gs[64][129];
  int t = threadIdx.x;
  int tx = t & 15, ty = t >> 4;
  float acc[8][8];
  #pragma unroll
  for (int u=0;u<8;u++)
    #pragma unroll
    for (int v=0;v<8;v++) acc[u][v]=0.f;
  float cs = 0.f;
  for (int r0 = blockIdx.x*64; r0 < N_; r0 += gridDim.x*64){
    __syncthreads();
    for (int idx = t; idx < 64*32; idx += 256){
      int r = idx >> 5, p = idx & 31;
      float4 v = {0.f,0.f,0.f,0.f};
      if (r0 + r < N_) v = ((const float4*)g)[(size_t)(r0+r)*32 + p];
      gs[r][p*4+0]=v.x; gs[r][p*4+1]=v.y; gs[r][p*4+2]=v.z; gs[r][p*4+3]=v.w;
    }
    __syncthreads();
    #pragma unroll 4
    for (int r=0;r<64;r++){
      float a[8], b[8];
      #pragma unroll
      for (int u=0;u<8;u++){ a[u]=gs[r][tx+16*u]; b[u]=gs[r][ty+16*u]; }
      #pragma unroll
      for (int u=0;u<8;u++)
        #pragma unroll
        for (int v=0;v<8;v++) acc[u][v] += a[u]*b[v];
    }
    if (t < 128){
      float c2=0.f;
      #pragma unroll 4
      for (int r=0;r<64;r++) c2 += gs[r][t];
      cs += c2;
    }
  }
  #pragma unroll
  for (int u=0;u<8;u++)
    #pragma unroll
    for (int v=0;v<8;v++)
      atomicAdd(&S2[(tx+16*u)*128 + (ty+16*v)], acc[u][v]);
  if (t < 128) atomicAdd(&colsum[t], cs);
}

// q[j] = w_j S2 w_j^T
__global__ void k_quad(const float* __restrict__ W1, const float* __restrict__ S2,
                       float* __restrict__ qbuf) {
  __shared__ float ws[128];
  __shared__ float red[128];
  int j = blockIdx.x, d = threadIdx.x;
  ws[d] = W1[(size_t)j*128 + d];
  __syncthreads();
  float r = 0.f;
  for (int dp=0; dp<128; dp++) r += S2[dp*128 + d]*ws[dp];
  red[d] = r*ws[d];
  __syncthreads();
  for (int off=64; off>0; off>>=1){ if (d<off) red[d]+=red[d+off]; __syncthreads(); }
  if (d==0) qbuf[j] = red[0];
}

// per-channel stats -> s (scale), and c (fused output bias)
__global__ void k_stats2(const float* __restrict__ W1, const float* __restrict__ b1,
                         const float* __restrict__ W2, const float* __restrict__ b2,
                         const float* __restrict__ gamma, const float* __restrict__ beta,
                         const float* __restrict__ eps1, const float* __restrict__ colsum,
                         const float* __restrict__ qbuf, float* __restrict__ sbuf,
                         float* __restrict__ cbuf, int N_) {
  __shared__ float mg[128];
  __shared__ float tt[256];
  int t = threadIdx.x;
  float invN = 1.f/(float)N_;
  if (t < 128) mg[t] = colsum[t]*invN;
  __syncthreads();
  float e1 = eps1[0];
  float bpp = (1.f + e1)*b1[t];
  const float* w = W1 + (size_t)t*128;
  float mx = bpp;
  for (int d=0; d<128; d++) mx += w[d]*mg[d];
  float ex2 = qbuf[t]*invN + 2.f*bpp*(mx - bpp) + bpp*bpp;
  float var = ex2 - mx*mx;
  float s = gamma[t]*rsqrtf(var + 1e-5f);
  sbuf[t] = s;
  tt[t] = (bpp - mx)*s + beta[t];
  __syncthreads();
  float c = b2[t];
  for (int j=0;j<256;j++) c += tt[j]*W2[(size_t)t*256 + j];
  cbuf[t] = c;
}

// M[k,d] = sum_j W2[k,j] * s[j] * W1[j,d]
__global__ void k_matM(const float* __restrict__ W1, const float* __restrict__ W2,
                       const float* __restrict__ sbuf, float* __restrict__ Mm) {
  __shared__ float ws[256];
  int k = blockIdx.x, d = threadIdx.x;
  ws[d]       = W2[(size_t)k*256 + d]       * sbuf[d];
  ws[d + 128] = W2[(size_t)k*256 + d + 128] * sbuf[d + 128];
  __syncthreads();
  float acc = 0.f;
  for (int j=0;j<256;j++) acc += ws[j]*W1[(size_t)j*128 + d];
  Mm[(size_t)k*128 + d] = acc;
}

// out[i,k] = g[i,:] . M[k,:] + c[k]
__global__ __launch_bounds__(256) void k_out(const float* __restrict__ g, const float* __restrict__ Mm,
                     const float* __restrict__ cb, float* __restrict__ out, int N_) {
  __shared__ float gs[64][33];
  __shared__ float Ms[256][33];
  int t = threadIdx.x;
  int tx = t & 15, ty = t >> 4;
  int i0 = blockIdx.x*64;
  float acc[4][16];
  #pragma unroll
  for (int r=0;r<4;r++)
    #pragma unroll
    for (int q=0;q<16;q++) acc[r][q]=0.f;
  for (int ch=0; ch<4; ch++){
    __syncthreads();
    #pragma unroll
    for (int l=0;l<2;l++){
      int idx = t + l*256;
      int r = idx >> 3, p = idx & 7;
      float4 v = {0.f,0.f,0.f,0.f};
      if (i0 + r < N_) v = *(const float4*)&g[(size_t)(i0+r)*128 + ch*32 + p*4];
      gs[r][p*4+0]=v.x; gs[r][p*4+1]=v.y; gs[r][p*4+2]=v.z; gs[r][p*4+3]=v.w;
    }
    #pragma unroll
    for (int l=0;l<8;l++){
      int idx = t + l*256;
      int q = idx >> 3, p = idx & 7;
      float4 v = *(const float4*)&Mm[(size_t)q*128 + ch*32 + p*4];
      Ms[q][p*4+0]=v.x; Ms[q][p*4+1]=v.y; Ms[q][p*4+2]=v.z; Ms[q][p*4+3]=v.w;
    }
    __syncthreads();
    #pragma unroll 4
    for (int dd=0; dd<32; dd++){
      float a[4], b[16];
      #pragma unroll
      for (int r=0;r<4;r++) a[r] = gs[tx*4+r][dd];
      #pragma unroll
      for (int q=0;q<16;q++) b[q] = Ms[ty*16+q][dd];
      #pragma unroll
      for (int r=0;r<4;r++)
        #pragma unroll
        for (int q=0;q<16;q++) acc[r][q] += a[r]*b[q];
    }
  }
  float cv[16];
  #pragma unroll
  for (int q=0;q<16;q++) cv[q] = cb[ty*16+q];
  #pragma unroll
  for (int r=0;r<4;r++){
    int i = i0 + tx*4 + r;
    if (i < N_){
      #pragma unroll
      for (int q4=0;q4<4;q4++){
        float4 o;
        o.x = acc[r][q4*4+0]+cv[q4*4+0];
        o.y = acc[r][q4*4+1]+cv[q4*4+1];
        o.z = acc[r][q4*4+2]+cv[q4*4+2];
        o.w = acc[r][q4*4+3]+cv[q4*4+3];
        *(float4*)&out[(size_t)i*256 + ty*16 + q4*4] = o;
      }
    }
  }
}

extern "C" void kernel_launch(void* const* d_in, const int* in_sizes, int n_in,
                              void* d_out, int out_size, void* d_ws, size_t ws_size,
                              hipStream_t stream) {
  const float* h     = (const float*)d_in[0];
  const int*   esrc  = (const int*)d_in[1];
  const int*   edst  = (const int*)d_in[2];
  const float* W1    = (const float*)d_in[3];
  const float* b1    = (const float*)d_in[4];
  const float* W2    = (const float*)d_in[5];
  const float* b2    = (const float*)d_in[6];
  const float* gamma = (const float*)d_in[7];
  const float* beta  = (const float*)d_in[8];
  const float* eps1  = (const float*)d_in[9];
  int N = in_sizes[0] / IN_DIM;
  int E = in_sizes[1];
  int B = (N + NPB - 1) / NPB;          // 391 buckets for N=100000
  float* out = (float*)d_out;

  char* ws = (char*)d_ws;
  size_t off = 0;
  auto alloc = [&](size_t bytes)->char* {
    char* p = ws + off; off = align256(off + bytes); return p;
  };
  int*    gcount  = (int*)   alloc((size_t)B*4);
  int*    boff    = (int*)   alloc(((size_t)B+1)*4);
  int*    gcursor = (int*)   alloc((size_t)B*4);
  int*    row_ptr = (int*)   alloc(((size_t)N+1)*4);
  uint32* pairs   = (uint32*)alloc((size_t)E*4);
  int*    eidx    = (int*)   alloc((size_t)E*4);
  uint32* hb      = (uint32*)alloc((size_t)N*IN_DIM*2);
  float*  S2      = (float*) alloc(128*128*4 + 128*4);
  float*  colsum  = S2 + 128*128;
  float*  qbuf    = (float*) alloc(256*4);
  float*  sbuf    = (float*) alloc(256*4);
  float*  cbuf    = (float*) alloc(256*4);
  float*  Mm      = (float*) alloc(256*128*4);
  float*  g       = (float*) alloc((size_t)N*128*4);
  (void)ws_size; (void)n_in; (void)out_size;

  hipMemsetAsync(gcount, 0, (size_t)B*4, stream);
  hipMemsetAsync(S2, 0, 128*128*4 + 128*4, stream);

  k_h2b   <<<2048, 256, 0, stream>>>(h, hb, N*IN_DIM/4);
  k_bcount<<<512, 256, 0, stream>>>(edst, gcount, E, B);
  k_bscan <<<1, 256, 0, stream>>>(gcount, boff, gcursor, row_ptr, B, N);
  k_bfill <<<256, 256, 0, stream>>>(esrc, edst, gcursor, pairs, E, B);
  k_bsort <<<B, 256, 0, stream>>>(pairs, boff, row_ptr, eidx, N);
  k_gather<<<(N+3)/4, 256, 0, stream>>>(hb, h, row_ptr, eidx, eps1, g, N);
  k_gram  <<<512, 256, 0, stream>>>(g, S2, colsum, N);
  k_quad  <<<256, 128, 0, stream>>>(W1, S2, qbuf);
  k_stats2<<<1, 256, 0, stream>>>(W1, b1, W2, b2, gamma, beta, eps1, colsum, qbuf, sbuf, cbuf, N);
  k_matM  <<<256, 128, 0, stream>>>(W1, W2, sbuf, Mm);
  k_out   <<<(N+63)/64, 256, 0, stream>>>(g, Mm, cbuf, out, N);
}

// Round 4
// 536.010 us; speedup vs baseline: 5.2065x; 1.0826x over previous
//
#include <hip/hip_runtime.h>
#include <cstdint>
#include <cstddef>

// Extractor_N2V folded: g = seg_sum(h[src],dst)/deg + eps1*h  (bf16 storage)
// BN stats analytically from colsum(g), S2 = G^T G; out = g @ M^T + c,
// M = W2 diag(s) W1 (bf16).  CSR via 2-level bucket sort (dst>>8).

#define IN_DIM 128
#define H_DIM 256
#define NPB 256
#define MAXB 1792

typedef unsigned int uint32;
typedef unsigned short ushort;
typedef __attribute__((ext_vector_type(8))) short short8;
typedef __attribute__((ext_vector_type(4))) float f32x4;

union U16B { uint4 u; short8 s; };

static inline size_t align256(size_t x){ return (x + 255) & ~(size_t)255; }

__device__ inline uint32 f2bf(float f){
  uint32 u = __float_as_uint(f);
  return (u + 0x7FFFu + ((u >> 16) & 1u)) >> 16;   // RNE
}

// ---- h (fp32) -> hb (bf16 packed, 2/uint)
__global__ __launch_bounds__(256) void k_h2b(const float* __restrict__ h,
                        uint32* __restrict__ hb2, int n4) {
  int i = blockIdx.x*256 + threadIdx.x;
  int stride = gridDim.x*256;
  for (; i < n4; i += stride) {
    float4 v = ((const float4*)h)[i];
    uint32 lo = f2bf(v.x) | (f2bf(v.y) << 16);
    uint32 hi = f2bf(v.z) | (f2bf(v.w) << 16);
    ((uint2*)hb2)[i] = make_uint2(lo, hi);
  }
}

// ---- bucket histogram
__global__ __launch_bounds__(256) void k_bcount(const int* __restrict__ dst,
                        int* __restrict__ gcount, int E_, int B_) {
  __shared__ int lc[512];
  int t = threadIdx.x;
  for (int i = t; i < B_; i += 256) lc[i] = 0;
  __syncthreads();
  int per = (E_ + gridDim.x - 1) / gridDim.x;
  int beg = blockIdx.x * per, end = min(beg + per, E_);
  for (int i = beg + t; i < end; i += 256) atomicAdd(&lc[dst[i] >> 8], 1);
  __syncthreads();
  for (int i = t; i < B_; i += 256) { int v = lc[i]; if (v) atomicAdd(&gcount[i], v); }
}

// ---- exclusive scan of bucket counts
__global__ __launch_bounds__(256) void k_bscan(const int* __restrict__ gcount,
                        int* __restrict__ boff, int* __restrict__ gcursor,
                        int* __restrict__ row_ptr, int B_, int N_) {
  __shared__ int part[256];
  __shared__ int vals[MAXB];
  int t = threadIdx.x;
  int base = t * 7;
  int s = 0;
  #pragma unroll
  for (int k = 0; k < 7; k++) {
    int idx = base + k;
    int v = (idx < B_) ? gcount[idx] : 0;
    vals[idx < MAXB ? idx : MAXB-1] = s;
    s += v;
  }
  part[t] = s;
  __syncthreads();
  for (int off = 1; off < 256; off <<= 1) {
    int a = (t >= off) ? part[t - off] : 0;
    __syncthreads();
    part[t] += a;
    __syncthreads();
  }
  int pbase = (t > 0) ? part[t - 1] : 0;
  #pragma unroll
  for (int k = 0; k < 7; k++) {
    int idx = base + k;
    if (idx < B_) { int o = pbase + vals[idx]; boff[idx] = o; gcursor[idx] = o; }
  }
  if (t == 255) { boff[B_] = part[255]; row_ptr[N_] = part[255]; }
}

// ---- chunked scatter into bucket-contiguous ranges
__global__ __launch_bounds__(256) void k_bfill(const int* __restrict__ src,
                        const int* __restrict__ dst, int* __restrict__ gcursor,
                        uint32* __restrict__ pairs, int E_, int B_) {
  __shared__ int lc[512];
  int t = threadIdx.x;
  for (int i = t; i < B_; i += 256) lc[i] = 0;
  __syncthreads();
  int per = (E_ + gridDim.x - 1) / gridDim.x;
  int beg = blockIdx.x * per, end = min(beg + per, E_);
  for (int i = beg + t; i < end; i += 256) atomicAdd(&lc[dst[i] >> 8], 1);
  __syncthreads();
  for (int i = t; i < B_; i += 256) {
    int v = lc[i];
    lc[i] = v ? atomicAdd(&gcursor[i], v) : 0;
  }
  __syncthreads();
  for (int i = beg + t; i < end; i += 256) {
    int d = dst[i];
    int b = d >> 8;
    int p = atomicAdd(&lc[b], 1);
    pairs[p] = (uint32)src[i] | ((uint32)(d & 255) << 20);
  }
}

// ---- per-bucket counting sort -> CSR
__global__ __launch_bounds__(256) void k_bsort(const uint32* __restrict__ pairs,
                        const int* __restrict__ boff, int* __restrict__ row_ptr,
                        int* __restrict__ eidx, int N_) {
  __shared__ int cnt[256];
  __shared__ int scan[256];
  __shared__ int cursor[256];
  int t = threadIdx.x, b = blockIdx.x;
  cnt[t] = 0;
  __syncthreads();
  int beg = boff[b], end = boff[b + 1];
  for (int i = beg + t; i < end; i += 256) atomicAdd(&cnt[pairs[i] >> 20], 1);
  __syncthreads();
  int v = cnt[t];
  scan[t] = v;
  __syncthreads();
  for (int off = 1; off < 256; off <<= 1) {
    int a = (t >= off) ? scan[t - off] : 0;
    __syncthreads();
    scan[t] += a;
    __syncthreads();
  }
  int ex = scan[t] - v;
  cursor[t] = ex;
  int node = b * NPB + t;
  if (node < N_) row_ptr[node] = beg + ex;
  __syncthreads();
  for (int i = beg + t; i < end; i += 256) {
    uint32 pk = pairs[i];
    int j = pk >> 20;
    int p = atomicAdd(&cursor[j], 1);
    eidx[beg + p] = (int)(pk & 0xFFFFF);
  }
}

// ---- one wave per node, bf16 rows in, bf16 g out
__global__ __launch_bounds__(256) void k_gather(const uint32* __restrict__ hb,
                        const int* __restrict__ row_ptr, const int* __restrict__ eidx,
                        const float* __restrict__ eps1, uint32* __restrict__ gb, int N_) {
  int w = (int)((blockIdx.x*blockDim.x + threadIdx.x) >> 6);
  w = __builtin_amdgcn_readfirstlane(w);
  int lane = threadIdx.x & 63;
  if (w >= N_) return;
  int beg = row_ptr[w], end = row_ptr[w+1];
  float2 a0 = {0.f,0.f}, a1 = {0.f,0.f}, a2 = {0.f,0.f}, a3 = {0.f,0.f};
  int e = beg;
  for (; e + 3 < end; e += 4) {
    int s0 = eidx[e], s1 = eidx[e+1], s2 = eidx[e+2], s3 = eidx[e+3];
    uint32 u0 = hb[(size_t)s0*64 + lane];
    uint32 u1 = hb[(size_t)s1*64 + lane];
    uint32 u2 = hb[(size_t)s2*64 + lane];
    uint32 u3 = hb[(size_t)s3*64 + lane];
    a0.x += __uint_as_float(u0 << 16); a0.y += __uint_as_float(u0 & 0xFFFF0000u);
    a1.x += __uint_as_float(u1 << 16); a1.y += __uint_as_float(u1 & 0xFFFF0000u);
    a2.x += __uint_as_float(u2 << 16); a2.y += __uint_as_float(u2 & 0xFFFF0000u);
    a3.x += __uint_as_float(u3 << 16); a3.y += __uint_as_float(u3 & 0xFFFF0000u);
  }
  for (; e < end; e++) {
    int s0 = eidx[e];
    uint32 u0 = hb[(size_t)s0*64 + lane];
    a0.x += __uint_as_float(u0 << 16); a0.y += __uint_as_float(u0 & 0xFFFF0000u);
  }
  float degf = (float)(end - beg);
  float e1 = eps1[0];
  uint32 hu = hb[(size_t)w*64 + lane];
  float ox = ((a0.x + a1.x) + (a2.x + a3.x)) / degf + e1 * __uint_as_float(hu << 16);
  float oy = ((a0.y + a1.y) + (a2.y + a3.y)) / degf + e1 * __uint_as_float(hu & 0xFFFF0000u);
  gb[(size_t)w*64 + lane] = f2bf(ox) | (f2bf(oy) << 16);
}

// ---- S2 partials + colsum partials per block (no atomics), bf16 input
__global__ __launch_bounds__(256) void k_gram(const uint32* __restrict__ gb,
                       float* __restrict__ slabs, int N_) {
  __shared__ float gs[64][132];
  int t = threadIdx.x;
  int tx = t & 15, ty = t >> 4;
  int ty4 = ty * 4;
  float acc[8][8];
  #pragma unroll
  for (int u=0;u<8;u++)
    #pragma unroll
    for (int v=0;v<8;v++) acc[u][v]=0.f;
  float cs = 0.f;
  for (int r0 = blockIdx.x*64; r0 < N_; r0 += gridDim.x*64){
    __syncthreads();
    for (int idx = t; idx < 64*64; idx += 256){
      int r = idx >> 6, p = idx & 63;
      uint32 u = 0;
      if (r0 + r < N_) u = gb[(size_t)(r0+r)*64 + p];
      float lo = __uint_as_float(u << 16);
      float hi = __uint_as_float(u & 0xFFFF0000u);
      *(float2*)&gs[r][2*p] = make_float2(lo, hi);
    }
    __syncthreads();
    #pragma unroll 4
    for (int r=0;r<64;r++){
      float4 b0 = *(float4*)&gs[r][ty4];
      float4 b1 = *(float4*)&gs[r][ty4 + 64];
      float a[8];
      #pragma unroll
      for (int u=0;u<8;u++) a[u]=gs[r][tx+16*u];
      #pragma unroll
      for (int u=0;u<8;u++){
        acc[u][0] += a[u]*b0.x; acc[u][1] += a[u]*b0.y;
        acc[u][2] += a[u]*b0.z; acc[u][3] += a[u]*b0.w;
        acc[u][4] += a[u]*b1.x; acc[u][5] += a[u]*b1.y;
        acc[u][6] += a[u]*b1.z; acc[u][7] += a[u]*b1.w;
      }
    }
    if (t < 128){
      float c2=0.f;
      #pragma unroll 4
      for (int r=0;r<64;r++) c2 += gs[r][t];
      cs += c2;
    }
  }
  float* slab = slabs + (size_t)blockIdx.x * 16512;
  #pragma unroll
  for (int u=0;u<8;u++){
    #pragma unroll
    for (int v2=0; v2<2; v2++){
      float4 o = make_float4(acc[u][v2*4+0], acc[u][v2*4+1], acc[u][v2*4+2], acc[u][v2*4+3]);
      *(float4*)&slab[(size_t)(tx+16*u)*128 + ty4 + 64*v2] = o;
    }
  }
  if (t < 128) slab[16384 + t] = cs;
}

// ---- reduce slabs -> S2 (16384) + colsum (128)
__global__ __launch_bounds__(256) void k_reduce(const float* __restrict__ slabs,
                        float* __restrict__ S2, float* __restrict__ colsum, int nslab) {
  int i = blockIdx.x*256 + threadIdx.x;
  if (i >= 16512) return;
  float s = 0.f;
  for (int k = 0; k < nslab; k++) s += slabs[(size_t)k*16512 + i];
  if (i < 16384) S2[i] = s; else colsum[i - 16384] = s;
}

// q[j] = w_j S2 w_j^T
__global__ void k_quad(const float* __restrict__ W1, const float* __restrict__ S2,
                       float* __restrict__ qbuf) {
  __shared__ float ws[128];
  __shared__ float red[128];
  int j = blockIdx.x, d = threadIdx.x;
  ws[d] = W1[(size_t)j*128 + d];
  __syncthreads();
  float r = 0.f;
  for (int dp=0; dp<128; dp++) r += S2[dp*128 + d]*ws[dp];
  red[d] = r*ws[d];
  __syncthreads();
  for (int off=64; off>0; off>>=1){ if (d<off) red[d]+=red[d+off]; __syncthreads(); }
  if (d==0) qbuf[j] = red[0];
}

// per-channel stats -> s (scale), and c (fused output bias)
__global__ void k_stats2(const float* __restrict__ W1, const float* __restrict__ b1,
                         const float* __restrict__ W2, const float* __restrict__ b2,
                         const float* __restrict__ gamma, const float* __restrict__ beta,
                         const float* __restrict__ eps1, const float* __restrict__ colsum,
                         const float* __restrict__ qbuf, float* __restrict__ sbuf,
                         float* __restrict__ cbuf, int N_) {
  __shared__ float mg[128];
  __shared__ float tt[256];
  int t = threadIdx.x;
  float invN = 1.f/(float)N_;
  if (t < 128) mg[t] = colsum[t]*invN;
  __syncthreads();
  float e1 = eps1[0];
  float bpp = (1.f + e1)*b1[t];
  const float* w = W1 + (size_t)t*128;
  float mx = bpp;
  for (int d=0; d<128; d++) mx += w[d]*mg[d];
  float ex2 = qbuf[t]*invN + 2.f*bpp*(mx - bpp) + bpp*bpp;
  float var = ex2 - mx*mx;
  float s = gamma[t]*rsqrtf(var + 1e-5f);
  sbuf[t] = s;
  tt[t] = (bpp - mx)*s + beta[t];
  __syncthreads();
  float c = b2[t];
  for (int j=0;j<256;j++) c += tt[j]*W2[(size_t)t*256 + j];
  cbuf[t] = c;
}

// M[k,d] = sum_j W2[k,j]*s[j]*W1[j,d]  -> bf16
__global__ void k_matM(const float* __restrict__ W1, const float* __restrict__ W2,
                       const float* __restrict__ sbuf, ushort* __restrict__ Mb) {
  __shared__ float ws[256];
  int k = blockIdx.x, d = threadIdx.x;
  ws[d]       = W2[(size_t)k*256 + d]       * sbuf[d];
  ws[d + 128] = W2[(size_t)k*256 + d + 128] * sbuf[d + 128];
  __syncthreads();
  float acc = 0.f;
  for (int j=0;j<256;j++) acc += ws[j]*W1[(size_t)j*128 + d];
  Mb[(size_t)k*128 + d] = (ushort)f2bf(acc);
}

// ---- out[i,k] = g[i,:].M[k,:] + c[k]  via mfma_f32_16x16x32_bf16
// A: lane m=l&15, k=(l>>4)*8+j (contig 16B from gb). B: lane n=l&15, same k
// (contig 16B from Mb rows). C/D: col=l&15, row=(l>>4)*4+reg.
__global__ __launch_bounds__(256) void k_out(const uint32* __restrict__ gb,
                     const ushort* __restrict__ Mb, const float* __restrict__ cb,
                     float* __restrict__ out, int N_) {
  int t = threadIdx.x;
  int l = t & 63, w = t >> 6;
  int m0 = blockIdx.x*64 + w*16;
  int lm = l & 15, lq = l >> 4;
  const uint4* gb4 = (const uint4*)gb;     // 16 uint4 per row (128 bf16)
  const uint4* Mb4 = (const uint4*)Mb;
  int arow = m0 + lm; if (arow > N_-1) arow = N_-1;
  U16B a[4];
  #pragma unroll
  for (int kc=0; kc<4; kc++) a[kc].u = gb4[(size_t)arow*16 + kc*4 + lq];
  f32x4 acc[16];
  #pragma unroll
  for (int nt=0; nt<16; nt++) acc[nt] = (f32x4)0.f;
  #pragma unroll
  for (int nt=0; nt<16; nt++){
    int nrow = nt*16 + lm;
    #pragma unroll
    for (int kc=0; kc<4; kc++){
      U16B b; b.u = Mb4[(size_t)nrow*16 + kc*4 + lq];
      acc[nt] = __builtin_amdgcn_mfma_f32_16x16x32_bf16(a[kc].s, b.s, acc[nt], 0, 0, 0);
    }
  }
  #pragma unroll
  for (int nt=0; nt<16; nt++){
    float cv = cb[nt*16 + lm];
    #pragma unroll
    for (int r=0; r<4; r++){
      int row = m0 + lq*4 + r;
      if (row < N_) out[(size_t)row*256 + nt*16 + lm] = acc[nt][r] + cv;
    }
  }
}

extern "C" void kernel_launch(void* const* d_in, const int* in_sizes, int n_in,
                              void* d_out, int out_size, void* d_ws, size_t ws_size,
                              hipStream_t stream) {
  const float* h     = (const float*)d_in[0];
  const int*   esrc  = (const int*)d_in[1];
  const int*   edst  = (const int*)d_in[2];
  const float* W1    = (const float*)d_in[3];
  const float* b1    = (const float*)d_in[4];
  const float* W2    = (const float*)d_in[5];
  const float* b2    = (const float*)d_in[6];
  const float* gamma = (const float*)d_in[7];
  const float* beta  = (const float*)d_in[8];
  const float* eps1  = (const float*)d_in[9];
  int N = in_sizes[0] / IN_DIM;
  int E = in_sizes[1];
  int B = (N + NPB - 1) / NPB;          // 391 for N=100000
  float* out = (float*)d_out;

  char* ws = (char*)d_ws;
  size_t off = 0;
  auto alloc = [&](size_t bytes)->char* {
    char* p = ws + off; off = align256(off + bytes); return p;
  };
  int*    gcount  = (int*)   alloc((size_t)B*4);
  int*    boff    = (int*)   alloc(((size_t)B+1)*4);
  int*    gcursor = (int*)   alloc((size_t)B*4);
  int*    row_ptr = (int*)   alloc(((size_t)N+1)*4);
  uint32* pairs   = (uint32*)alloc((size_t)E*4);
  int*    eidx    = (int*)   alloc((size_t)E*4);
  uint32* hb      = (uint32*)alloc((size_t)N*IN_DIM/2*4);
  uint32* gb      = (uint32*)alloc((size_t)N*IN_DIM/2*4);
  float*  S2      = (float*) alloc(16384*4);
  float*  colsum  = (float*) alloc(128*4);
  float*  qbuf    = (float*) alloc(256*4);
  float*  sbuf    = (float*) alloc(256*4);
  float*  cbuf    = (float*) alloc(256*4);
  ushort* Mb      = (ushort*)alloc(256*128*2);
  // slabs take the remaining workspace (cap 512)
  size_t slab_bytes = (size_t)16512*4;
  int nslab = (int)((ws_size > off + slab_bytes) ? (ws_size - off) / slab_bytes : 1);
  if (nslab > 512) nslab = 512;
  if (nslab < 64)  nslab = (nslab < 1) ? 1 : nslab;
  float* slabs = (float*)alloc((size_t)nslab * slab_bytes);
  (void)n_in; (void)out_size;

  hipMemsetAsync(gcount, 0, (size_t)B*4, stream);

  k_h2b   <<<1024, 256, 0, stream>>>(h, hb, N*IN_DIM/4);
  k_bcount<<<512, 256, 0, stream>>>(edst, gcount, E, B);
  k_bscan <<<1, 256, 0, stream>>>(gcount, boff, gcursor, row_ptr, B, N);
  k_bfill <<<256, 256, 0, stream>>>(esrc, edst, gcursor, pairs, E, B);
  k_bsort <<<B, 256, 0, stream>>>(pairs, boff, row_ptr, eidx, N);
  k_gather<<<(N+3)/4, 256, 0, stream>>>(hb, row_ptr, eidx, eps1, gb, N);
  k_gram  <<<nslab, 256, 0, stream>>>(gb, slabs, N);
  k_reduce<<<(16512+255)/256, 256, 0, stream>>>(slabs, S2, colsum, nslab);
  k_quad  <<<256, 128, 0, stream>>>(W1, S2, qbuf);
  k_stats2<<<1, 256, 0, stream>>>(W1, b1, W2, b2, gamma, beta, eps1, colsum, qbuf, sbuf, cbuf, N);
  k_matM  <<<256, 128, 0, stream>>>(W1, W2, sbuf, Mb);
  k_out   <<<(N+63)/64, 256, 0, stream>>>(gb, Mb, cbuf, out, N);
}

// Round 5
// 422.430 us; speedup vs baseline: 6.6064x; 1.2689x over previous
//
#include <hip/hip_runtime.h>
#include <cstdint>
#include <cstddef>

// Extractor_N2V folded: g = seg_sum(h[src],dst)/deg + eps1*h  (bf16 storage)
// BN stats analytically from colsum(g), S2 = G^T G; out = g @ M^T + c,
// M = W2 diag(s) W1 (bf16).  CSR via 2-level bucket sort (dst>>8).

#define IN_DIM 128
#define H_DIM 256
#define NPB 256
#define MAXB 1792

typedef unsigned int uint32;
typedef unsigned short ushort;
typedef __attribute__((ext_vector_type(8))) short short8;
typedef __attribute__((ext_vector_type(4))) float f32x4;

union U16B { uint4 u; short8 s; };

static inline size_t align256(size_t x){ return (x + 255) & ~(size_t)255; }

__device__ inline uint32 f2bf(float f){
  uint32 u = __float_as_uint(f);
  return (u + 0x7FFFu + ((u >> 16) & 1u)) >> 16;   // RNE
}

// ---- h (fp32) -> hb (bf16 packed, 2/uint)
__global__ __launch_bounds__(256) void k_h2b(const float* __restrict__ h,
                        uint32* __restrict__ hb2, int n4) {
  int i = blockIdx.x*256 + threadIdx.x;
  int stride = gridDim.x*256;
  for (; i < n4; i += stride) {
    float4 v = ((const float4*)h)[i];
    uint32 lo = f2bf(v.x) | (f2bf(v.y) << 16);
    uint32 hi = f2bf(v.z) | (f2bf(v.w) << 16);
    ((uint2*)hb2)[i] = make_uint2(lo, hi);
  }
}

// ---- bucket histogram
__global__ __launch_bounds__(256) void k_bcount(const int* __restrict__ dst,
                        int* __restrict__ gcount, int E_, int B_) {
  __shared__ int lc[512];
  int t = threadIdx.x;
  for (int i = t; i < B_; i += 256) lc[i] = 0;
  __syncthreads();
  int per = (E_ + gridDim.x - 1) / gridDim.x;
  int beg = blockIdx.x * per, end = min(beg + per, E_);
  for (int i = beg + t; i < end; i += 256) atomicAdd(&lc[dst[i] >> 8], 1);
  __syncthreads();
  for (int i = t; i < B_; i += 256) { int v = lc[i]; if (v) atomicAdd(&gcount[i], v); }
}

// ---- exclusive scan of bucket counts
__global__ __launch_bounds__(256) void k_bscan(const int* __restrict__ gcount,
                        int* __restrict__ boff, int* __restrict__ gcursor,
                        int* __restrict__ row_ptr, int B_, int N_) {
  __shared__ int part[256];
  __shared__ int vals[MAXB];
  int t = threadIdx.x;
  int base = t * 7;
  int s = 0;
  #pragma unroll
  for (int k = 0; k < 7; k++) {
    int idx = base + k;
    int v = (idx < B_) ? gcount[idx] : 0;
    vals[idx < MAXB ? idx : MAXB-1] = s;
    s += v;
  }
  part[t] = s;
  __syncthreads();
  for (int off = 1; off < 256; off <<= 1) {
    int a = (t >= off) ? part[t - off] : 0;
    __syncthreads();
    part[t] += a;
    __syncthreads();
  }
  int pbase = (t > 0) ? part[t - 1] : 0;
  #pragma unroll
  for (int k = 0; k < 7; k++) {
    int idx = base + k;
    if (idx < B_) { int o = pbase + vals[idx]; boff[idx] = o; gcursor[idx] = o; }
  }
  if (t == 255) { boff[B_] = part[255]; row_ptr[N_] = part[255]; }
}

// ---- chunked scatter into bucket-contiguous ranges
__global__ __launch_bounds__(256) void k_bfill(const int* __restrict__ src,
                        const int* __restrict__ dst, int* __restrict__ gcursor,
                        uint32* __restrict__ pairs, int E_, int B_) {
  __shared__ int lc[512];
  int t = threadIdx.x;
  for (int i = t; i < B_; i += 256) lc[i] = 0;
  __syncthreads();
  int per = (E_ + gridDim.x - 1) / gridDim.x;
  int beg = blockIdx.x * per, end = min(beg + per, E_);
  for (int i = beg + t; i < end; i += 256) atomicAdd(&lc[dst[i] >> 8], 1);
  __syncthreads();
  for (int i = t; i < B_; i += 256) {
    int v = lc[i];
    lc[i] = v ? atomicAdd(&gcursor[i], v) : 0;
  }
  __syncthreads();
  for (int i = beg + t; i < end; i += 256) {
    int d = dst[i];
    int b = d >> 8;
    int p = atomicAdd(&lc[b], 1);
    pairs[p] = (uint32)src[i] | ((uint32)(d & 255) << 20);
  }
}

// ---- per-bucket counting sort -> CSR
__global__ __launch_bounds__(256) void k_bsort(const uint32* __restrict__ pairs,
                        const int* __restrict__ boff, int* __restrict__ row_ptr,
                        int* __restrict__ eidx, int N_) {
  __shared__ int cnt[256];
  __shared__ int scan[256];
  __shared__ int cursor[256];
  int t = threadIdx.x, b = blockIdx.x;
  cnt[t] = 0;
  __syncthreads();
  int beg = boff[b], end = boff[b + 1];
  for (int i = beg + t; i < end; i += 256) atomicAdd(&cnt[pairs[i] >> 20], 1);
  __syncthreads();
  int v = cnt[t];
  scan[t] = v;
  __syncthreads();
  for (int off = 1; off < 256; off <<= 1) {
    int a = (t >= off) ? scan[t - off] : 0;
    __syncthreads();
    scan[t] += a;
    __syncthreads();
  }
  int ex = scan[t] - v;
  cursor[t] = ex;
  int node = b * NPB + t;
  if (node < N_) row_ptr[node] = beg + ex;
  __syncthreads();
  for (int i = beg + t; i < end; i += 256) {
    uint32 pk = pairs[i];
    int j = pk >> 20;
    int p = atomicAdd(&cursor[j], 1);
    eidx[beg + p] = (int)(pk & 0xFFFFF);
  }
}

// ---- one wave per node, bf16 rows in, bf16 g out
__global__ __launch_bounds__(256) void k_gather(const uint32* __restrict__ hb,
                        const int* __restrict__ row_ptr, const int* __restrict__ eidx,
                        const float* __restrict__ eps1, uint32* __restrict__ gb, int N_) {
  int w = (int)((blockIdx.x*blockDim.x + threadIdx.x) >> 6);
  w = __builtin_amdgcn_readfirstlane(w);
  int lane = threadIdx.x & 63;
  if (w >= N_) return;
  int beg = row_ptr[w], end = row_ptr[w+1];
  float2 a0 = {0.f,0.f}, a1 = {0.f,0.f}, a2 = {0.f,0.f}, a3 = {0.f,0.f};
  int e = beg;
  for (; e + 3 < end; e += 4) {
    int s0 = eidx[e], s1 = eidx[e+1], s2 = eidx[e+2], s3 = eidx[e+3];
    uint32 u0 = hb[(size_t)s0*64 + lane];
    uint32 u1 = hb[(size_t)s1*64 + lane];
    uint32 u2 = hb[(size_t)s2*64 + lane];
    uint32 u3 = hb[(size_t)s3*64 + lane];
    a0.x += __uint_as_float(u0 << 16); a0.y += __uint_as_float(u0 & 0xFFFF0000u);
    a1.x += __uint_as_float(u1 << 16); a1.y += __uint_as_float(u1 & 0xFFFF0000u);
    a2.x += __uint_as_float(u2 << 16); a2.y += __uint_as_float(u2 & 0xFFFF0000u);
    a3.x += __uint_as_float(u3 << 16); a3.y += __uint_as_float(u3 & 0xFFFF0000u);
  }
  for (; e < end; e++) {
    int s0 = eidx[e];
    uint32 u0 = hb[(size_t)s0*64 + lane];
    a0.x += __uint_as_float(u0 << 16); a0.y += __uint_as_float(u0 & 0xFFFF0000u);
  }
  float degf = (float)(end - beg);
  float e1 = eps1[0];
  uint32 hu = hb[(size_t)w*64 + lane];
  float ox = ((a0.x + a1.x) + (a2.x + a3.x)) / degf + e1 * __uint_as_float(hu << 16);
  float oy = ((a0.y + a1.y) + (a2.y + a3.y)) / degf + e1 * __uint_as_float(hu & 0xFFFF0000u);
  gb[(size_t)w*64 + lane] = f2bf(ox) | (f2bf(oy) << 16);
}

// ---- S2 partials + colsum partials per block (no atomics), bf16 input
__global__ __launch_bounds__(256) void k_gram(const uint32* __restrict__ gb,
                       float* __restrict__ slabs, int N_) {
  __shared__ float gs[64][132];
  int t = threadIdx.x;
  int tx = t & 15, ty = t >> 4;
  int ty4 = ty * 4;
  float acc[8][8];
  #pragma unroll
  for (int u=0;u<8;u++)
    #pragma unroll
    for (int v=0;v<8;v++) acc[u][v]=0.f;
  float cs = 0.f;
  for (int r0 = blockIdx.x*64; r0 < N_; r0 += gridDim.x*64){
    __syncthreads();
    for (int idx = t; idx < 64*64; idx += 256){
      int r = idx >> 6, p = idx & 63;
      uint32 u = 0;
      if (r0 + r < N_) u = gb[(size_t)(r0+r)*64 + p];
      float lo = __uint_as_float(u << 16);
      float hi = __uint_as_float(u & 0xFFFF0000u);
      *(float2*)&gs[r][2*p] = make_float2(lo, hi);
    }
    __syncthreads();
    #pragma unroll 4
    for (int r=0;r<64;r++){
      float4 b0 = *(float4*)&gs[r][ty4];
      float4 b1 = *(float4*)&gs[r][ty4 + 64];
      float a[8];
      #pragma unroll
      for (int u=0;u<8;u++) a[u]=gs[r][tx+16*u];
      #pragma unroll
      for (int u=0;u<8;u++){
        acc[u][0] += a[u]*b0.x; acc[u][1] += a[u]*b0.y;
        acc[u][2] += a[u]*b0.z; acc[u][3] += a[u]*b0.w;
        acc[u][4] += a[u]*b1.x; acc[u][5] += a[u]*b1.y;
        acc[u][6] += a[u]*b1.z; acc[u][7] += a[u]*b1.w;
      }
    }
    if (t < 128){
      float c2=0.f;
      #pragma unroll 4
      for (int r=0;r<64;r++) c2 += gs[r][t];
      cs += c2;
    }
  }
  float* slab = slabs + (size_t)blockIdx.x * 16512;
  #pragma unroll
  for (int u=0;u<8;u++){
    #pragma unroll
    for (int v2=0; v2<2; v2++){
      float4 o = make_float4(acc[u][v2*4+0], acc[u][v2*4+1], acc[u][v2*4+2], acc[u][v2*4+3]);
      *(float4*)&slab[(size_t)(tx+16*u)*128 + ty4 + 64*v2] = o;
    }
  }
  if (t < 128) slab[16384 + t] = cs;
}

// ---- parallel reduce: grid.y slab-groups, atomicAdd into S2cs[16512]
__global__ __launch_bounds__(256) void k_reduce(const float* __restrict__ slabs,
                        float* __restrict__ S2cs, int nslab, int per) {
  int i = blockIdx.x*256 + threadIdx.x;
  if (i >= 16512) return;
  int k0 = blockIdx.y * per;
  int k1 = min(k0 + per, nslab);
  float s = 0.f;
  for (int k = k0; k < k1; k++) s += slabs[(size_t)k*16512 + i];
  atomicAdd(&S2cs[i], s);
}

// q[j] = w_j S2 w_j^T
__global__ void k_quad(const float* __restrict__ W1, const float* __restrict__ S2,
                       float* __restrict__ qbuf) {
  __shared__ float ws[128];
  __shared__ float red[128];
  int j = blockIdx.x, d = threadIdx.x;
  ws[d] = W1[(size_t)j*128 + d];
  __syncthreads();
  float r = 0.f;
  for (int dp=0; dp<128; dp++) r += S2[dp*128 + d]*ws[dp];
  red[d] = r*ws[d];
  __syncthreads();
  for (int off=64; off>0; off>>=1){ if (d<off) red[d]+=red[d+off]; __syncthreads(); }
  if (d==0) qbuf[j] = red[0];
}

// per-channel stats -> s (scale), and c (fused output bias)
__global__ void k_stats2(const float* __restrict__ W1, const float* __restrict__ b1,
                         const float* __restrict__ W2, const float* __restrict__ b2,
                         const float* __restrict__ gamma, const float* __restrict__ beta,
                         const float* __restrict__ eps1, const float* __restrict__ colsum,
                         const float* __restrict__ qbuf, float* __restrict__ sbuf,
                         float* __restrict__ cbuf, int N_) {
  __shared__ float mg[128];
  __shared__ float tt[256];
  int t = threadIdx.x;
  float invN = 1.f/(float)N_;
  if (t < 128) mg[t] = colsum[t]*invN;
  __syncthreads();
  float e1 = eps1[0];
  float bpp = (1.f + e1)*b1[t];
  const float* w = W1 + (size_t)t*128;
  float mx = bpp;
  for (int d=0; d<128; d++) mx += w[d]*mg[d];
  float ex2 = qbuf[t]*invN + 2.f*bpp*(mx - bpp) + bpp*bpp;
  float var = ex2 - mx*mx;
  float s = gamma[t]*rsqrtf(var + 1e-5f);
  sbuf[t] = s;
  tt[t] = (bpp - mx)*s + beta[t];
  __syncthreads();
  float c = b2[t];
  for (int j=0;j<256;j++) c += tt[j]*W2[(size_t)t*256 + j];
  cbuf[t] = c;
}

// M[k,d] = sum_j W2[k,j]*s[j]*W1[j,d]  -> bf16
__global__ void k_matM(const float* __restrict__ W1, const float* __restrict__ W2,
                       const float* __restrict__ sbuf, ushort* __restrict__ Mb) {
  __shared__ float ws[256];
  int k = blockIdx.x, d = threadIdx.x;
  ws[d]       = W2[(size_t)k*256 + d]       * sbuf[d];
  ws[d + 128] = W2[(size_t)k*256 + d + 128] * sbuf[d + 128];
  __syncthreads();
  float acc = 0.f;
  for (int j=0;j<256;j++) acc += ws[j]*W1[(size_t)j*128 + d];
  Mb[(size_t)k*128 + d] = (ushort)f2bf(acc);
}

// ---- out[i,k] = g[i,:].M[k,:] + c[k]  via mfma_f32_16x16x32_bf16
__global__ __launch_bounds__(256) void k_out(const uint32* __restrict__ gb,
                     const ushort* __restrict__ Mb, const float* __restrict__ cb,
                     float* __restrict__ out, int N_) {
  int t = threadIdx.x;
  int l = t & 63, w = t >> 6;
  int m0 = blockIdx.x*64 + w*16;
  int lm = l & 15, lq = l >> 4;
  const uint4* gb4 = (const uint4*)gb;     // 16 uint4 per row (128 bf16)
  const uint4* Mb4 = (const uint4*)Mb;
  int arow = m0 + lm; if (arow > N_-1) arow = N_-1;
  U16B a[4];
  #pragma unroll
  for (int kc=0; kc<4; kc++) a[kc].u = gb4[(size_t)arow*16 + kc*4 + lq];
  f32x4 acc[16];
  #pragma unroll
  for (int nt=0; nt<16; nt++) acc[nt] = (f32x4)0.f;
  #pragma unroll
  for (int nt=0; nt<16; nt++){
    int nrow = nt*16 + lm;
    #pragma unroll
    for (int kc=0; kc<4; kc++){
      U16B b; b.u = Mb4[(size_t)nrow*16 + kc*4 + lq];
      acc[nt] = __builtin_amdgcn_mfma_f32_16x16x32_bf16(a[kc].s, b.s, acc[nt], 0, 0, 0);
    }
  }
  #pragma unroll
  for (int nt=0; nt<16; nt++){
    float cv = cb[nt*16 + lm];
    #pragma unroll
    for (int r=0; r<4; r++){
      int row = m0 + lq*4 + r;
      if (row < N_) out[(size_t)row*256 + nt*16 + lm] = acc[nt][r] + cv;
    }
  }
}

extern "C" void kernel_launch(void* const* d_in, const int* in_sizes, int n_in,
                              void* d_out, int out_size, void* d_ws, size_t ws_size,
                              hipStream_t stream) {
  const float* h     = (const float*)d_in[0];
  const int*   esrc  = (const int*)d_in[1];
  const int*   edst  = (const int*)d_in[2];
  const float* W1    = (const float*)d_in[3];
  const float* b1    = (const float*)d_in[4];
  const float* W2    = (const float*)d_in[5];
  const float* b2    = (const float*)d_in[6];
  const float* gamma = (const float*)d_in[7];
  const float* beta  = (const float*)d_in[8];
  const float* eps1  = (const float*)d_in[9];
  int N = in_sizes[0] / IN_DIM;
  int E = in_sizes[1];
  int B = (N + NPB - 1) / NPB;          // 391 for N=100000
  float* out = (float*)d_out;

  char* ws = (char*)d_ws;
  size_t off = 0;
  auto alloc = [&](size_t bytes)->char* {
    char* p = ws + off; off = align256(off + bytes); return p;
  };
  int*    gcount  = (int*)   alloc((size_t)B*4);
  int*    boff    = (int*)   alloc(((size_t)B+1)*4);
  int*    gcursor = (int*)   alloc((size_t)B*4);
  int*    row_ptr = (int*)   alloc(((size_t)N+1)*4);
  uint32* pairs   = (uint32*)alloc((size_t)E*4);
  int*    eidx    = (int*)   alloc((size_t)E*4);
  uint32* hb      = (uint32*)alloc((size_t)N*IN_DIM/2*4);
  uint32* gb      = (uint32*)alloc((size_t)N*IN_DIM/2*4);
  float*  S2cs    = (float*) alloc(16512*4);          // S2[16384] + colsum[128]
  float*  S2      = S2cs;
  float*  colsum  = S2cs + 16384;
  float*  qbuf    = (float*) alloc(256*4);
  float*  sbuf    = (float*) alloc(256*4);
  float*  cbuf    = (float*) alloc(256*4);
  ushort* Mb      = (ushort*)alloc(256*128*2);
  size_t slab_bytes = (size_t)16512*4;
  int nslab = (int)((ws_size > off + slab_bytes) ? (ws_size - off) / slab_bytes : 1);
  if (nslab > 512) nslab = 512;
  if (nslab < 1)  nslab = 1;
  float* slabs = (float*)alloc((size_t)nslab * slab_bytes);
  (void)n_in; (void)out_size;

  hipMemsetAsync(gcount, 0, (size_t)B*4, stream);
  hipMemsetAsync(S2cs, 0, 16512*4, stream);

  k_h2b   <<<1024, 256, 0, stream>>>(h, hb, N*IN_DIM/4);
  k_bcount<<<512, 256, 0, stream>>>(edst, gcount, E, B);
  k_bscan <<<1, 256, 0, stream>>>(gcount, boff, gcursor, row_ptr, B, N);
  k_bfill <<<256, 256, 0, stream>>>(esrc, edst, gcursor, pairs, E, B);
  k_bsort <<<B, 256, 0, stream>>>(pairs, boff, row_ptr, eidx, N);
  k_gather<<<(N+3)/4, 256, 0, stream>>>(hb, row_ptr, eidx, eps1, gb, N);
  k_gram  <<<nslab, 256, 0, stream>>>(gb, slabs, N);
  {
    int ngrp = 32;
    int per = (nslab + ngrp - 1) / ngrp;
    dim3 rgrid((16512 + 255)/256, ngrp);
    k_reduce<<<rgrid, 256, 0, stream>>>(slabs, S2cs, nslab, per);
  }
  k_quad  <<<256, 128, 0, stream>>>(W1, S2, qbuf);
  k_stats2<<<1, 256, 0, stream>>>(W1, b1, W2, b2, gamma, beta, eps1, colsum, qbuf, sbuf, cbuf, N);
  k_matM  <<<256, 128, 0, stream>>>(W1, W2, sbuf, Mb);
  k_out   <<<(N+63)/64, 256, 0, stream>>>(gb, Mb, cbuf, out, N);
}

// Round 6
// 415.749 us; speedup vs baseline: 6.7126x; 1.0161x over previous
//
#include <hip/hip_runtime.h>
#include <cstdint>
#include <cstddef>

// Extractor_N2V folded: g = seg_sum(h[src],dst)/deg + eps1*h  (bf16 storage)
// BN stats analytically from colsum(g), S2 = G^T G; out = g @ M^T + c,
// M = W2 diag(s) W1 (bf16).  CSR via 2-level bucket sort (dst>>8).
// R6: gather uses 16-lane x dwordx4 row loads (4 edges per VMEM inst).

#define IN_DIM 128
#define H_DIM 256
#define NPB 256
#define MAXB 1792

typedef unsigned int uint32;
typedef unsigned short ushort;
typedef __attribute__((ext_vector_type(8))) short short8;
typedef __attribute__((ext_vector_type(4))) float f32x4;

union U16B { uint4 u; short8 s; };

static inline size_t align256(size_t x){ return (x + 255) & ~(size_t)255; }

__device__ inline uint32 f2bf(float f){
  uint32 u = __float_as_uint(f);
  return (u + 0x7FFFu + ((u >> 16) & 1u)) >> 16;   // RNE
}
__device__ inline float bflo(uint32 u){ return __uint_as_float(u << 16); }
__device__ inline float bfhi(uint32 u){ return __uint_as_float(u & 0xFFFF0000u); }

// ---- h (fp32) -> hb (bf16 packed, 2/uint)
__global__ __launch_bounds__(256) void k_h2b(const float* __restrict__ h,
                        uint32* __restrict__ hb2, int n4) {
  int i = blockIdx.x*256 + threadIdx.x;
  int stride = gridDim.x*256;
  for (; i < n4; i += stride) {
    float4 v = ((const float4*)h)[i];
    uint32 lo = f2bf(v.x) | (f2bf(v.y) << 16);
    uint32 hi = f2bf(v.z) | (f2bf(v.w) << 16);
    ((uint2*)hb2)[i] = make_uint2(lo, hi);
  }
}

// ---- bucket histogram
__global__ __launch_bounds__(256) void k_bcount(const int* __restrict__ dst,
                        int* __restrict__ gcount, int E_, int B_) {
  __shared__ int lc[512];
  int t = threadIdx.x;
  for (int i = t; i < B_; i += 256) lc[i] = 0;
  __syncthreads();
  int per = (E_ + gridDim.x - 1) / gridDim.x;
  int beg = blockIdx.x * per, end = min(beg + per, E_);
  for (int i = beg + t; i < end; i += 256) atomicAdd(&lc[dst[i] >> 8], 1);
  __syncthreads();
  for (int i = t; i < B_; i += 256) { int v = lc[i]; if (v) atomicAdd(&gcount[i], v); }
}

// ---- exclusive scan of bucket counts
__global__ __launch_bounds__(256) void k_bscan(const int* __restrict__ gcount,
                        int* __restrict__ boff, int* __restrict__ gcursor,
                        int* __restrict__ row_ptr, int B_, int N_) {
  __shared__ int part[256];
  __shared__ int vals[MAXB];
  int t = threadIdx.x;
  int base = t * 7;
  int s = 0;
  #pragma unroll
  for (int k = 0; k < 7; k++) {
    int idx = base + k;
    int v = (idx < B_) ? gcount[idx] : 0;
    vals[idx < MAXB ? idx : MAXB-1] = s;
    s += v;
  }
  part[t] = s;
  __syncthreads();
  for (int off = 1; off < 256; off <<= 1) {
    int a = (t >= off) ? part[t - off] : 0;
    __syncthreads();
    part[t] += a;
    __syncthreads();
  }
  int pbase = (t > 0) ? part[t - 1] : 0;
  #pragma unroll
  for (int k = 0; k < 7; k++) {
    int idx = base + k;
    if (idx < B_) { int o = pbase + vals[idx]; boff[idx] = o; gcursor[idx] = o; }
  }
  if (t == 255) { boff[B_] = part[255]; row_ptr[N_] = part[255]; }
}

// ---- chunked scatter into bucket-contiguous ranges
__global__ __launch_bounds__(256) void k_bfill(const int* __restrict__ src,
                        const int* __restrict__ dst, int* __restrict__ gcursor,
                        uint32* __restrict__ pairs, int E_, int B_) {
  __shared__ int lc[512];
  int t = threadIdx.x;
  for (int i = t; i < B_; i += 256) lc[i] = 0;
  __syncthreads();
  int per = (E_ + gridDim.x - 1) / gridDim.x;
  int beg = blockIdx.x * per, end = min(beg + per, E_);
  for (int i = beg + t; i < end; i += 256) atomicAdd(&lc[dst[i] >> 8], 1);
  __syncthreads();
  for (int i = t; i < B_; i += 256) {
    int v = lc[i];
    lc[i] = v ? atomicAdd(&gcursor[i], v) : 0;
  }
  __syncthreads();
  for (int i = beg + t; i < end; i += 256) {
    int d = dst[i];
    int b = d >> 8;
    int p = atomicAdd(&lc[b], 1);
    pairs[p] = (uint32)src[i] | ((uint32)(d & 255) << 20);
  }
}

// ---- per-bucket counting sort -> CSR (512 threads)
__global__ __launch_bounds__(512) void k_bsort(const uint32* __restrict__ pairs,
                        const int* __restrict__ boff, int* __restrict__ row_ptr,
                        int* __restrict__ eidx, int N_) {
  __shared__ int cnt[256];
  __shared__ int scan[256];
  __shared__ int cursor[256];
  int t = threadIdx.x, b = blockIdx.x;
  if (t < 256) cnt[t] = 0;
  __syncthreads();
  int beg = boff[b], end = boff[b + 1];
  for (int i = beg + t; i < end; i += 512) atomicAdd(&cnt[pairs[i] >> 20], 1);
  __syncthreads();
  int v = (t < 256) ? cnt[t] : 0;
  if (t < 256) scan[t] = v;
  __syncthreads();
  for (int off = 1; off < 256; off <<= 1) {
    int a = (t >= off && t < 256) ? scan[t - off] : 0;
    __syncthreads();
    if (t < 256) scan[t] += a;
    __syncthreads();
  }
  if (t < 256) {
    int ex = scan[t] - v;
    cursor[t] = ex;
    int node = b * NPB + t;
    if (node < N_) row_ptr[node] = beg + ex;
  }
  __syncthreads();
  for (int i = beg + t; i < end; i += 512) {
    uint32 pk = pairs[i];
    int j = pk >> 20;
    int p = atomicAdd(&cursor[j], 1);
    eidx[beg + p] = (int)(pk & 0xFFFFF);
  }
}

// ---- one wave per node; 4 lane-groups of 16, dwordx4 row loads (4 edges/inst)
__global__ __launch_bounds__(256) void k_gather(const uint32* __restrict__ hb,
                        const int* __restrict__ row_ptr, const int* __restrict__ eidx,
                        const float* __restrict__ eps1, uint32* __restrict__ gb, int N_) {
  int w = (int)((blockIdx.x*blockDim.x + threadIdx.x) >> 6);
  int lane = threadIdx.x & 63;
  if (w >= N_) return;
  int g = lane >> 4, lm = lane & 15;
  int beg = row_ptr[w], end = row_ptr[w+1];
  const uint4* hb4 = (const uint4*)hb;
  float a0[8], a1[8];
  #pragma unroll
  for (int j=0;j<8;j++){ a0[j]=0.f; a1[j]=0.f; }
  int e = beg;
  for (; e + 7 < end; e += 8) {
    int s0 = eidx[e + g];
    int s1 = eidx[e + 4 + g];
    uint4 u0 = hb4[(size_t)s0*16 + lm];
    uint4 u1 = hb4[(size_t)s1*16 + lm];
    a0[0] += bflo(u0.x); a0[1] += bfhi(u0.x);
    a0[2] += bflo(u0.y); a0[3] += bfhi(u0.y);
    a0[4] += bflo(u0.z); a0[5] += bfhi(u0.z);
    a0[6] += bflo(u0.w); a0[7] += bfhi(u0.w);
    a1[0] += bflo(u1.x); a1[1] += bfhi(u1.x);
    a1[2] += bflo(u1.y); a1[3] += bfhi(u1.y);
    a1[4] += bflo(u1.z); a1[5] += bfhi(u1.z);
    a1[6] += bflo(u1.w); a1[7] += bfhi(u1.w);
  }
  for (; e < end; e += 4) {
    if (e + g < end) {
      int s0 = eidx[e + g];
      uint4 u0 = hb4[(size_t)s0*16 + lm];
      a0[0] += bflo(u0.x); a0[1] += bfhi(u0.x);
      a0[2] += bflo(u0.y); a0[3] += bfhi(u0.y);
      a0[4] += bflo(u0.z); a0[5] += bfhi(u0.z);
      a0[6] += bflo(u0.w); a0[7] += bfhi(u0.w);
    }
  }
  #pragma unroll
  for (int j=0;j<8;j++){
    float v = a0[j] + a1[j];
    v += __shfl_xor(v, 16, 64);
    v += __shfl_xor(v, 32, 64);
    a0[j] = v;
  }
  float degf = (float)(end - beg);
  float e1 = eps1[0];
  uint4 hu = hb4[(size_t)w*16 + lm];
  float hres[8] = { bflo(hu.x), bfhi(hu.x), bflo(hu.y), bfhi(hu.y),
                    bflo(hu.z), bfhi(hu.z), bflo(hu.w), bfhi(hu.w) };
  if (g == 0) {
    float o[8];
    #pragma unroll
    for (int j=0;j<8;j++) o[j] = a0[j]/degf + e1*hres[j];
    uint4 ou;
    ou.x = f2bf(o[0]) | (f2bf(o[1]) << 16);
    ou.y = f2bf(o[2]) | (f2bf(o[3]) << 16);
    ou.z = f2bf(o[4]) | (f2bf(o[5]) << 16);
    ou.w = f2bf(o[6]) | (f2bf(o[7]) << 16);
    ((uint4*)gb)[(size_t)w*16 + lm] = ou;
  }
}

// ---- S2 partials + colsum partials per block (no atomics), bf16 input
__global__ __launch_bounds__(256) void k_gram(const uint32* __restrict__ gb,
                       float* __restrict__ slabs, int N_) {
  __shared__ float gs[64][132];
  int t = threadIdx.x;
  int tx = t & 15, ty = t >> 4;
  int ty4 = ty * 4;
  float acc[8][8];
  #pragma unroll
  for (int u=0;u<8;u++)
    #pragma unroll
    for (int v=0;v<8;v++) acc[u][v]=0.f;
  float cs = 0.f;
  for (int r0 = blockIdx.x*64; r0 < N_; r0 += gridDim.x*64){
    __syncthreads();
    for (int idx = t; idx < 64*64; idx += 256){
      int r = idx >> 6, p = idx & 63;
      uint32 u = 0;
      if (r0 + r < N_) u = gb[(size_t)(r0+r)*64 + p];
      *(float2*)&gs[r][2*p] = make_float2(bflo(u), bfhi(u));
    }
    __syncthreads();
    #pragma unroll 4
    for (int r=0;r<64;r++){
      float4 b0 = *(float4*)&gs[r][ty4];
      float4 b1 = *(float4*)&gs[r][ty4 + 64];
      float a[8];
      #pragma unroll
      for (int u=0;u<8;u++) a[u]=gs[r][tx+16*u];
      #pragma unroll
      for (int u=0;u<8;u++){
        acc[u][0] += a[u]*b0.x; acc[u][1] += a[u]*b0.y;
        acc[u][2] += a[u]*b0.z; acc[u][3] += a[u]*b0.w;
        acc[u][4] += a[u]*b1.x; acc[u][5] += a[u]*b1.y;
        acc[u][6] += a[u]*b1.z; acc[u][7] += a[u]*b1.w;
      }
    }
    if (t < 128){
      float c2=0.f;
      #pragma unroll 4
      for (int r=0;r<64;r++) c2 += gs[r][t];
      cs += c2;
    }
  }
  float* slab = slabs + (size_t)blockIdx.x * 16512;
  #pragma unroll
  for (int u=0;u<8;u++){
    #pragma unroll
    for (int v2=0; v2<2; v2++){
      float4 o = make_float4(acc[u][v2*4+0], acc[u][v2*4+1], acc[u][v2*4+2], acc[u][v2*4+3]);
      *(float4*)&slab[(size_t)(tx+16*u)*128 + ty4 + 64*v2] = o;
    }
  }
  if (t < 128) slab[16384 + t] = cs;
}

// ---- parallel reduce: grid.y slab-groups, atomicAdd into S2cs[16512]
__global__ __launch_bounds__(256) void k_reduce(const float* __restrict__ slabs,
                        float* __restrict__ S2cs, int nslab, int per) {
  int i = blockIdx.x*256 + threadIdx.x;
  if (i >= 16512) return;
  int k0 = blockIdx.y * per;
  int k1 = min(k0 + per, nslab);
  float s = 0.f;
  for (int k = k0; k < k1; k++) s += slabs[(size_t)k*16512 + i];
  atomicAdd(&S2cs[i], s);
}

// q[j] = w_j S2 w_j^T
__global__ void k_quad(const float* __restrict__ W1, const float* __restrict__ S2,
                       float* __restrict__ qbuf) {
  __shared__ float ws[128];
  __shared__ float red[128];
  int j = blockIdx.x, d = threadIdx.x;
  ws[d] = W1[(size_t)j*128 + d];
  __syncthreads();
  float r = 0.f;
  for (int dp=0; dp<128; dp++) r += S2[dp*128 + d]*ws[dp];
  red[d] = r*ws[d];
  __syncthreads();
  for (int off=64; off>0; off>>=1){ if (d<off) red[d]+=red[d+off]; __syncthreads(); }
  if (d==0) qbuf[j] = red[0];
}

// per-channel stats -> s (scale), and c (fused output bias)
__global__ void k_stats2(const float* __restrict__ W1, const float* __restrict__ b1,
                         const float* __restrict__ W2, const float* __restrict__ b2,
                         const float* __restrict__ gamma, const float* __restrict__ beta,
                         const float* __restrict__ eps1, const float* __restrict__ colsum,
                         const float* __restrict__ qbuf, float* __restrict__ sbuf,
                         float* __restrict__ cbuf, int N_) {
  __shared__ float mg[128];
  __shared__ float tt[256];
  int t = threadIdx.x;
  float invN = 1.f/(float)N_;
  if (t < 128) mg[t] = colsum[t]*invN;
  __syncthreads();
  float e1 = eps1[0];
  float bpp = (1.f + e1)*b1[t];
  const float* w = W1 + (size_t)t*128;
  float mx = bpp;
  for (int d=0; d<128; d++) mx += w[d]*mg[d];
  float ex2 = qbuf[t]*invN + 2.f*bpp*(mx - bpp) + bpp*bpp;
  float var = ex2 - mx*mx;
  float s = gamma[t]*rsqrtf(var + 1e-5f);
  sbuf[t] = s;
  tt[t] = (bpp - mx)*s + beta[t];
  __syncthreads();
  float c = b2[t];
  for (int j=0;j<256;j++) c += tt[j]*W2[(size_t)t*256 + j];
  cbuf[t] = c;
}

// M[k,d] = sum_j W2[k,j]*s[j]*W1[j,d]  -> bf16
__global__ void k_matM(const float* __restrict__ W1, const float* __restrict__ W2,
                       const float* __restrict__ sbuf, ushort* __restrict__ Mb) {
  __shared__ float ws[256];
  int k = blockIdx.x, d = threadIdx.x;
  ws[d]       = W2[(size_t)k*256 + d]       * sbuf[d];
  ws[d + 128] = W2[(size_t)k*256 + d + 128] * sbuf[d + 128];
  __syncthreads();
  float acc = 0.f;
  for (int j=0;j<256;j++) acc += ws[j]*W1[(size_t)j*128 + d];
  Mb[(size_t)k*128 + d] = (ushort)f2bf(acc);
}

// ---- out[i,k] = g[i,:].M[k,:] + c[k]  via mfma_f32_16x16x32_bf16
__global__ __launch_bounds__(256) void k_out(const uint32* __restrict__ gb,
                     const ushort* __restrict__ Mb, const float* __restrict__ cb,
                     float* __restrict__ out, int N_) {
  int t = threadIdx.x;
  int l = t & 63, w = t >> 6;
  int m0 = blockIdx.x*64 + w*16;
  int lm = l & 15, lq = l >> 4;
  const uint4* gb4 = (const uint4*)gb;     // 16 uint4 per row (128 bf16)
  const uint4* Mb4 = (const uint4*)Mb;
  int arow = m0 + lm; if (arow > N_-1) arow = N_-1;
  U16B a[4];
  #pragma unroll
  for (int kc=0; kc<4; kc++) a[kc].u = gb4[(size_t)arow*16 + kc*4 + lq];
  f32x4 acc[16];
  #pragma unroll
  for (int nt=0; nt<16; nt++) acc[nt] = (f32x4)0.f;
  #pragma unroll
  for (int nt=0; nt<16; nt++){
    int nrow = nt*16 + lm;
    #pragma unroll
    for (int kc=0; kc<4; kc++){
      U16B b; b.u = Mb4[(size_t)nrow*16 + kc*4 + lq];
      acc[nt] = __builtin_amdgcn_mfma_f32_16x16x32_bf16(a[kc].s, b.s, acc[nt], 0, 0, 0);
    }
  }
  #pragma unroll
  for (int nt=0; nt<16; nt++){
    float cv = cb[nt*16 + lm];
    #pragma unroll
    for (int r=0; r<4; r++){
      int row = m0 + lq*4 + r;
      if (row < N_) out[(size_t)row*256 + nt*16 + lm] = acc[nt][r] + cv;
    }
  }
}

extern "C" void kernel_launch(void* const* d_in, const int* in_sizes, int n_in,
                              void* d_out, int out_size, void* d_ws, size_t ws_size,
                              hipStream_t stream) {
  const float* h     = (const float*)d_in[0];
  const int*   esrc  = (const int*)d_in[1];
  const int*   edst  = (const int*)d_in[2];
  const float* W1    = (const float*)d_in[3];
  const float* b1    = (const float*)d_in[4];
  const float* W2    = (const float*)d_in[5];
  const float* b2    = (const float*)d_in[6];
  const float* gamma = (const float*)d_in[7];
  const float* beta  = (const float*)d_in[8];
  const float* eps1  = (const float*)d_in[9];
  int N = in_sizes[0] / IN_DIM;
  int E = in_sizes[1];
  int B = (N + NPB - 1) / NPB;          // 391 for N=100000
  float* out = (float*)d_out;

  char* ws = (char*)d_ws;
  size_t off = 0;
  auto alloc = [&](size_t bytes)->char* {
    char* p = ws + off; off = align256(off + bytes); return p;
  };
  int*    gcount  = (int*)   alloc((size_t)B*4);
  int*    boff    = (int*)   alloc(((size_t)B+1)*4);
  int*    gcursor = (int*)   alloc((size_t)B*4);
  int*    row_ptr = (int*)   alloc(((size_t)N+1)*4);
  uint32* pairs   = (uint32*)alloc((size_t)E*4);
  int*    eidx    = (int*)   alloc((size_t)E*4);
  uint32* hb      = (uint32*)alloc((size_t)N*IN_DIM/2*4);
  uint32* gb      = (uint32*)alloc((size_t)N*IN_DIM/2*4);
  float*  S2cs    = (float*) alloc(16512*4);          // S2[16384] + colsum[128]
  float*  S2      = S2cs;
  float*  colsum  = S2cs + 16384;
  float*  qbuf    = (float*) alloc(256*4);
  float*  sbuf    = (float*) alloc(256*4);
  float*  cbuf    = (float*) alloc(256*4);
  ushort* Mb      = (ushort*)alloc(256*128*2);
  size_t slab_bytes = (size_t)16512*4;
  int nslab = (int)((ws_size > off + slab_bytes) ? (ws_size - off) / slab_bytes : 1);
  if (nslab > 512) nslab = 512;
  if (nslab < 1)  nslab = 1;
  float* slabs = (float*)alloc((size_t)nslab * slab_bytes);
  (void)n_in; (void)out_size;

  hipMemsetAsync(gcount, 0, (size_t)B*4, stream);
  hipMemsetAsync(S2cs, 0, 16512*4, stream);

  k_h2b   <<<1024, 256, 0, stream>>>(h, hb, N*IN_DIM/4);
  k_bcount<<<512, 256, 0, stream>>>(edst, gcount, E, B);
  k_bscan <<<1, 256, 0, stream>>>(gcount, boff, gcursor, row_ptr, B, N);
  k_bfill <<<512, 256, 0, stream>>>(esrc, edst, gcursor, pairs, E, B);
  k_bsort <<<B, 512, 0, stream>>>(pairs, boff, row_ptr, eidx, N);
  k_gather<<<(N+3)/4, 256, 0, stream>>>(hb, row_ptr, eidx, eps1, gb, N);
  k_gram  <<<nslab, 256, 0, stream>>>(gb, slabs, N);
  {
    int ngrp = 32;
    int per = (nslab + ngrp - 1) / ngrp;
    dim3 rgrid((16512 + 255)/256, ngrp);
    k_reduce<<<rgrid, 256, 0, stream>>>(slabs, S2cs, nslab, per);
  }
  k_quad  <<<256, 128, 0, stream>>>(W1, S2, qbuf);
  k_stats2<<<1, 256, 0, stream>>>(W1, b1, W2, b2, gamma, beta, eps1, colsum, qbuf, sbuf, cbuf, N);
  k_matM  <<<256, 128, 0, stream>>>(W1, W2, sbuf, Mb);
  k_out   <<<(N+63)/64, 256, 0, stream>>>(gb, Mb, cbuf, out, N);
}